// Round 1
// 2563.502 us; speedup vs baseline: 1.0937x; 1.0937x over previous
//
#include <hip/hip_runtime.h>
#include <cstdint>
#include <cstddef>

#define SS 12
#define NN 16384
#define EE 262144
#define TT 3072          // SS*NN/BB

typedef _Float16 h2_t __attribute__((ext_vector_type(2)));
typedef short bf16x8 __attribute__((ext_vector_type(8)));
typedef float floatx4 __attribute__((ext_vector_type(4)));
typedef unsigned short ushortx8 __attribute__((ext_vector_type(8)));

// ---------- helpers ----------
__device__ __forceinline__ float fast_sig(float x) {
    float e = __builtin_amdgcn_exp2f(-1.442695041f * x);   // exp(-x)
    return __builtin_amdgcn_rcpf(1.f + e);
}
__device__ __forceinline__ float fast_tanh(float x) {
    float e = __builtin_amdgcn_exp2f(2.885390082f * x);    // exp(2x); inf-safe
    return 1.f - 2.f * __builtin_amdgcn_rcpf(e + 1.f);
}
__device__ __forceinline__ unsigned short f2bf(float f) {
    unsigned int x = __float_as_uint(f);
    unsigned int r = (x + 0x7FFFu + ((x >> 16) & 1u)) >> 16;
    return (unsigned short)r;
}
__device__ __forceinline__ float bf2f(unsigned short u) {
    return __uint_as_float(((unsigned int)u) << 16);
}
__device__ __forceinline__ h2_t u2h(unsigned int u) {
    union { unsigned int u; h2_t h; } c; c.u = u; return c.h;
}
// swap adjacent lanes (l ^ 1) via quad_perm(1,0,3,2) — VALU, no LDS
__device__ __forceinline__ float dpp_xor1(float x) {
    int i = __builtin_amdgcn_mov_dpp(__float_as_int(x), 0xB1, 0xF, 0xF, true);
    return __int_as_float(i);
}

// ---------- zero counts ----------
__global__ void k_zero(int* __restrict__ p) {
    p[blockIdx.x * 256 + threadIdx.x] = 0;
}

// ---------- CSR build ----------
__global__ void k_count(const int* __restrict__ adj, int* __restrict__ counts) {
    int i = blockIdx.x * 256 + threadIdx.x;          // over SS*EE
    int t = i / EE, e = i - t * EE;
    int dst = adj[(size_t)t * 2 * EE + e];
    atomicAdd(&counts[t * NN + dst], 1);
}

__global__ void k_scan(const int* __restrict__ counts, int* __restrict__ offs,
                       int* __restrict__ cursor) {
    __shared__ int sums[1024];
    int t = blockIdx.x, tid = threadIdx.x;
    const int per = NN / 1024;                       // 16
    int base = t * NN + tid * per;
    int local[16];
    int s = 0;
#pragma unroll
    for (int i = 0; i < per; i++) { local[i] = counts[base + i]; s += local[i]; }
    sums[tid] = s;
    __syncthreads();
    for (int off = 1; off < 1024; off <<= 1) {
        int v = (tid >= off) ? sums[tid - off] : 0;
        __syncthreads();
        sums[tid] += v;
        __syncthreads();
    }
    int run = sums[tid] - s;                         // exclusive
#pragma unroll
    for (int i = 0; i < per; i++) { offs[base + i] = run; cursor[base + i] = run; run += local[i]; }
}

__global__ void k_scatter(const int* __restrict__ adj, const float* __restrict__ vals,
                          int* __restrict__ cursor, int2* __restrict__ edges) {
    int i = blockIdx.x * 256 + threadIdx.x;
    int t = i / EE, e = i - t * EE;
    int dst = adj[(size_t)t * 2 * EE + e];
    int src = adj[(size_t)t * 2 * EE + EE + e];
    float v = vals[(size_t)t * EE + e];
    int p = atomicAdd(&cursor[t * NN + dst], 1);
    edges[(size_t)t * EE + p] = make_int2(src, __float_as_int(v));
}

// ---------- support = xs @ gcn_weight  (fp32 acc, bf16 out) ----------
__global__ __launch_bounds__(256) void k_support(const float* __restrict__ xs,
                                                 const float* __restrict__ W,
                                                 unsigned short* __restrict__ sup) {
    __shared__ float Ash[64][128];
    __shared__ float Wsh[128][128];
    int tid = threadIdx.x;
    size_t rowbase = (size_t)blockIdx.x * 64;
    const float4* xa = (const float4*)(xs + rowbase * 128);
    float4* As = (float4*)&Ash[0][0];
#pragma unroll
    for (int q = 0; q < 8; q++) As[tid + q * 256] = xa[tid + q * 256];
    const float4* wg = (const float4*)W;
    float4* Ws = (float4*)&Wsh[0][0];
#pragma unroll
    for (int q = 0; q < 16; q++) Ws[tid + q * 256] = wg[tid + q * 256];
    __syncthreads();
    int jg = tid & 31, rg = tid >> 5;
    float acc[8][4];
#pragma unroll
    for (int i = 0; i < 8; i++)
#pragma unroll
        for (int j = 0; j < 4; j++) acc[i][j] = 0.f;
    for (int k4 = 0; k4 < 128; k4 += 4) {
        float4 a[8];
#pragma unroll
        for (int i = 0; i < 8; i++) a[i] = *(const float4*)&Ash[rg * 8 + i][k4];
#pragma unroll
        for (int kk = 0; kk < 4; kk++) {
            float4 wv = *(const float4*)&Wsh[k4 + kk][jg * 4];
#pragma unroll
            for (int i = 0; i < 8; i++) {
                float av = (kk == 0) ? a[i].x : (kk == 1) ? a[i].y : (kk == 2) ? a[i].z : a[i].w;
                acc[i][0] += av * wv.x; acc[i][1] += av * wv.y;
                acc[i][2] += av * wv.z; acc[i][3] += av * wv.w;
            }
        }
    }
#pragma unroll
    for (int i = 0; i < 8; i++) {
        ushort4 o;
        o.x = f2bf(acc[i][0]); o.y = f2bf(acc[i][1]);
        o.z = f2bf(acc[i][2]); o.w = f2bf(acc[i][3]);
        *(ushort4*)&sup[(rowbase + rg * 8 + i) * 128 + jg * 4] = o;
    }
}

// ---------- gather-reduce: wave per node, 2 dims per lane ----------
__global__ __launch_bounds__(256) void k_gather(const int2* __restrict__ edges,
                         const int* __restrict__ offs,
                         const int* __restrict__ ends,
                         const unsigned short* __restrict__ sup,
                         const float* __restrict__ bias,
                         unsigned short* __restrict__ cur) {
    int bn = blockIdx.x * 4 + (threadIdx.x >> 6);     // t*NN + n, wave-uniform
    bn = __builtin_amdgcn_readfirstlane(bn);
    int t = bn >> 14;
    int l = threadIdx.x & 63;
    int beg = offs[bn];
    int end = ends[bn];
    const unsigned short* supt = sup + (size_t)t * NN * 128;
    const int2* eg = edges + (size_t)t * EE;
    float acc0 = 0.f, acc1 = 0.f;                     // dims 2l, 2l+1
    int p = beg;
    for (; p + 3 < end; p += 4) {
        int2 e0 = eg[p], e1 = eg[p + 1], e2 = eg[p + 2], e3 = eg[p + 3];
        unsigned int u0 = *(const unsigned int*)&supt[(size_t)e0.x * 128 + 2 * l];
        unsigned int u1 = *(const unsigned int*)&supt[(size_t)e1.x * 128 + 2 * l];
        unsigned int u2 = *(const unsigned int*)&supt[(size_t)e2.x * 128 + 2 * l];
        unsigned int u3 = *(const unsigned int*)&supt[(size_t)e3.x * 128 + 2 * l];
        float w0 = __int_as_float(e0.y), w1 = __int_as_float(e1.y);
        float w2 = __int_as_float(e2.y), w3 = __int_as_float(e3.y);
        acc0 += w0 * bf2f((unsigned short)u0); acc1 += w0 * bf2f((unsigned short)(u0 >> 16));
        acc0 += w1 * bf2f((unsigned short)u1); acc1 += w1 * bf2f((unsigned short)(u1 >> 16));
        acc0 += w2 * bf2f((unsigned short)u2); acc1 += w2 * bf2f((unsigned short)(u2 >> 16));
        acc0 += w3 * bf2f((unsigned short)u3); acc1 += w3 * bf2f((unsigned short)(u3 >> 16));
    }
    for (; p < end; p++) {
        int2 e0 = eg[p];
        unsigned int u0 = *(const unsigned int*)&supt[(size_t)e0.x * 128 + 2 * l];
        float w0 = __int_as_float(e0.y);
        acc0 += w0 * bf2f((unsigned short)u0);
        acc1 += w0 * bf2f((unsigned short)(u0 >> 16));
    }
    float r0 = acc0 + bias[2 * l];
    float r1 = acc1 + bias[2 * l + 1];
    ushort2 o;
    o.x = f2bf(r0 > 0.f ? r0 : 0.f);
    o.y = f2bf(r1 > 0.f ? r1 : 0.f);
    *(ushort2*)&cur[(size_t)bn * 128 + 2 * l] = o;
}

// ---------- gates_x = cur @ w_ih^T + (b_ih+b_hh), bf16 MFMA ----------
// grid (3072, 8), 256 thr. Block: rows 64 (M), gates 64 (N), K=128.
// Output written PERMUTED into k_lstm's thread order:
//   gate gcol = (q<<7)|j  (q: 0=i,1=f,2=g,3=o; j=element)
//   slot = (q>>1)*256 + (j>>5)*64 + (j&31)*2 + (q&1)
// so k_lstm thread tid reads slots tid (i/f) and 256+tid (g/o) contiguously.
__global__ __launch_bounds__(256) void k_xgates(const unsigned short* __restrict__ cur,
                                                const float* __restrict__ wih,
                                                const float* __restrict__ bih,
                                                const float* __restrict__ bhh,
                                                unsigned short* __restrict__ gx) {
    __shared__ __align__(16) unsigned short At[64][136];   // +8 pad: 2-way banks
    __shared__ __align__(16) unsigned short Bt[64][136];
    int tid = threadIdx.x;
    size_t rowbase = (size_t)blockIdx.x * 64;
    int gbase = blockIdx.y * 64;
    // A tile: 64x128 bf16, 16B chunks
#pragma unroll
    for (int q = 0; q < 4; q++) {
        int idx = tid + q * 256;          // 0..1023 (16 chunks per row)
        int r = idx >> 4;
        int cc = (idx & 15) * 8;
        *(ushortx8*)&At[r][cc] = *(const ushortx8*)&cur[(rowbase + r) * 128 + cc];
    }
    // B tile: wih rows gbase..gbase+64, fp32 -> bf16 on the fly
#pragma unroll
    for (int q = 0; q < 8; q++) {
        int idx = tid + q * 256;          // 0..2047 (32 float4 per row)
        int r = idx >> 5;
        int c4 = (idx & 31) * 4;
        float4 v = *(const float4*)&wih[(size_t)(gbase + r) * 128 + c4];
        ushort4 o;
        o.x = f2bf(v.x); o.y = f2bf(v.y); o.z = f2bf(v.z); o.w = f2bf(v.w);
        *(ushort4*)&Bt[r][c4] = o;
    }
    __syncthreads();
    int wave = tid >> 6, lane = tid & 63;
    int m0 = wave * 16;
    int rin = lane & 15;
    int koff = (lane >> 4) * 8;
    floatx4 acc[4];
#pragma unroll
    for (int n = 0; n < 4; n++) acc[n] = (floatx4){0.f, 0.f, 0.f, 0.f};
#pragma unroll
    for (int kc = 0; kc < 4; kc++) {
        bf16x8 a = *(const bf16x8*)&At[m0 + rin][kc * 32 + koff];
#pragma unroll
        for (int n = 0; n < 4; n++) {
            bf16x8 b = *(const bf16x8*)&Bt[n * 16 + rin][kc * 32 + koff];
            acc[n] = __builtin_amdgcn_mfma_f32_16x16x32_bf16(a, b, acc[n], 0, 0, 0);
        }
    }
    // C/D: col = lane&15, row = (lane>>4)*4 + reg
    int rq = (lane >> 4) * 4;
#pragma unroll
    for (int n = 0; n < 4; n++) {
        int gcol = gbase + n * 16 + rin;
        float bs = bih[gcol] + bhh[gcol];
        int qg = gcol >> 7, jj = gcol & 127;
        int slot = ((qg >> 1) << 8) | ((jj >> 5) << 6) | ((jj & 31) << 1) | (qg & 1);
#pragma unroll
        for (int i = 0; i < 4; i++) {
            size_t row = rowbase + m0 + rq + i;
            gx[row * 512 + slot] = f2bf(acc[n][i] + bs);
        }
    }
}

// ---------- persistent LSTM: 64 blocks x 256 thr ----------
// Lane-pair (l, l^1) owns element j = wave*32 + (l>>1):
//   even lane: gates i[j] (r0) and g[j] (r1);  odd lane: f[j] (r0), o[j] (r1).
// Gate exchange is a single quad_perm DPP swap (no LDS, no extra barrier).
// All 256 threads update c/h redundantly (pair-identical, bitwise).
// h double-buffered in LDS -> exactly ONE barrier per step.
__global__ __launch_bounds__(256, 1) void k_lstm(const unsigned short* __restrict__ gx,
                                                 const float* __restrict__ whh,
                                                 const float* __restrict__ h0,
                                                 const float* __restrict__ c0,
                                                 float* __restrict__ out) {
    __shared__ __align__(8) _Float16 hsh[2][128];   // double-buffered h (f16)
    int b = blockIdx.x, tid = threadIdx.x;
    int l = tid & 63, w = tid >> 6;
    int j = w * 32 + (l >> 1);
    bool even = (l & 1) == 0;
    int gate0 = even ? j : 128 + j;          // i[j] or f[j]
    int gate1 = even ? 256 + j : 384 + j;    // g[j] or o[j]
    // act1 = Aa*sig(Ss*r1)+Bb : even -> tanh(r1), odd -> sig(r1)  (branchless)
    float Ss = even ? 2.f : 1.f;
    float Aa = even ? 2.f : 1.f;
    float Bb = even ? -1.f : 0.f;

    // weights: rows gate0 and gate1, packed f16 pairs (64+64 = 128 VGPRs)
    h2_t w0[64], w1[64];
    {
        const float4* r0p = (const float4*)(whh + (size_t)gate0 * 128);
        const float4* r1p = (const float4*)(whh + (size_t)gate1 * 128);
#pragma unroll
        for (int q = 0; q < 32; q++) {
            float4 v = r0p[q];
            h2_t p0; p0.x = (_Float16)v.x; p0.y = (_Float16)v.y;
            h2_t p1; p1.x = (_Float16)v.z; p1.y = (_Float16)v.w;
            w0[2 * q] = p0; w0[2 * q + 1] = p1;
        }
#pragma unroll
        for (int q = 0; q < 32; q++) {
            float4 v = r1p[q];
            h2_t p0; p0.x = (_Float16)v.x; p0.y = (_Float16)v.y;
            h2_t p1; p1.x = (_Float16)v.z; p1.y = (_Float16)v.w;
            w1[2 * q] = p0; w1[2 * q + 1] = p1;
        }
    }
    float c = c0[(size_t)b * 128 + j];        // pair-redundant copy
    if (tid < 128) hsh[0][tid] = (_Float16)h0[(size_t)b * 128 + tid];
    __syncthreads();

    // prefetch gx two steps deep (slots tid / tid+256 by k_xgates permutation)
    unsigned short nA0 = gx[(size_t)b * 512 + tid];
    unsigned short nA1 = gx[(size_t)b * 512 + 256 + tid];
    unsigned short nB0 = gx[((size_t)64 + b) * 512 + tid];
    unsigned short nB1 = gx[((size_t)64 + b) * 512 + 256 + tid];

#define LSTM_STEP(T, RD, WR)                                               \
    {                                                                      \
        unsigned int hv = *(const unsigned int*)&hsh[RD][2 * l];           \
        float px0 = bf2f(nA0), px1 = bf2f(nA1);                            \
        int tp2 = ((T) + 2 < TT) ? (T) + 2 : TT - 1;                       \
        const unsigned short* gp = gx + ((size_t)tp2 * 64 + b) * 512;      \
        unsigned short nC0 = gp[tid];                                      \
        unsigned short nC1 = gp[tid + 256];                                \
        float a00 = 0.f, a01 = 0.f, a10 = 0.f, a11 = 0.f;                  \
        _Pragma("unroll")                                                  \
        for (int mm = 0; mm < 64; mm += 2) {                               \
            unsigned int s0 = __builtin_amdgcn_readlane(hv, mm);           \
            unsigned int s1 = __builtin_amdgcn_readlane(hv, mm + 1);       \
            a00 = __builtin_amdgcn_fdot2(w0[mm], u2h(s0), a00, false);     \
            a10 = __builtin_amdgcn_fdot2(w1[mm], u2h(s0), a10, false);     \
            a01 = __builtin_amdgcn_fdot2(w0[mm + 1], u2h(s1), a01, false); \
            a11 = __builtin_amdgcn_fdot2(w1[mm + 1], u2h(s1), a11, false); \
        }                                                                  \
        float r0 = a00 + a01 + px0;                                        \
        float r1 = a10 + a11 + px1;                                        \
        float act0 = fast_sig(r0);                                         \
        float act1 = Aa * fast_sig(Ss * r1) + Bb;                          \
        float q0 = dpp_xor1(act0);                                         \
        float q1 = dpp_xor1(act1);                                         \
        float gi = even ? act0 : q0;                                       \
        float gf = even ? q0 : act0;                                       \
        float gg = even ? act1 : q1;                                       \
        float go = even ? q1 : act1;                                       \
        c = gf * c + gi * gg;                                              \
        float hn = go * fast_tanh(c);                                      \
        if (even) {                                                        \
            hsh[WR][j] = (_Float16)hn;                                     \
            out[((size_t)(T) * 64 + b) * 128 + j] = hn;                    \
        }                                                                  \
        __syncthreads();                                                   \
        nA0 = nB0; nA1 = nB1; nB0 = nC0; nB1 = nC1;                        \
    }

    for (int t = 0; t < TT; t += 2) {
        LSTM_STEP(t, 0, 1);
        LSTM_STEP(t + 1, 1, 0);
    }
#undef LSTM_STEP
}

// ---------- launcher ----------
extern "C" void kernel_launch(void* const* d_in, const int* in_sizes, int n_in,
                              void* d_out, int out_size, void* d_ws, size_t ws_size,
                              hipStream_t stream) {
    const int* adj    = (const int*)d_in[0];
    const float* vals = (const float*)d_in[1];
    const float* xs   = (const float*)d_in[2];
    const float* gw   = (const float*)d_in[3];
    const float* gb   = (const float*)d_in[4];
    const float* wih  = (const float*)d_in[5];
    const float* whh  = (const float*)d_in[6];
    const float* bih  = (const float*)d_in[7];
    const float* bhh  = (const float*)d_in[8];
    const float* h0   = (const float*)d_in[9];
    const float* c0   = (const float*)d_in[10];
    float* out = (float*)d_out;

    // Workspace layout (peak concurrent = 251,658,240 B):
    //   [0, 50,331,648)             cur (bf16, S*N*128)
    //   [50,331,648, 251,658,240)   gx  (bf16, S*N*512)
    // Aliased INSIDE the gx region (dead before k_xgates writes gx):
    //   support @ gx+0, counts/offs/cursor/edges after it.
    char* ws = (char*)d_ws;
    unsigned short* cur = (unsigned short*)(ws);
    unsigned short* gx  = (unsigned short*)(ws + 50331648);
    unsigned short* sup = (unsigned short*)(ws + 50331648);
    int* counts         = (int*)(ws + 100663296);
    int* offs           = (int*)(ws + 101449728);
    int* cursor         = (int*)(ws + 102236160);
    int2* edges         = (int2*)(ws + 103022592);

    k_zero<<<(SS * NN) / 256, 256, 0, stream>>>(counts);
    k_count<<<(SS * EE) / 256, 256, 0, stream>>>(adj, counts);
    k_scan<<<SS, 1024, 0, stream>>>(counts, offs, cursor);
    k_scatter<<<(SS * EE) / 256, 256, 0, stream>>>(adj, vals, cursor, edges);
    k_support<<<(SS * NN) / 64, 256, 0, stream>>>(xs, gw, sup);
    k_gather<<<(SS * NN) / 4, 256, 0, stream>>>(edges, offs, cursor, sup, gb, cur);
    k_xgates<<<dim3((SS * NN) / 64, 8), 256, 0, stream>>>(cur, wih, bih, bhh, gx);
    k_lstm<<<64, 256, 0, stream>>>(gx, whh, h0, c0, out);
}

// Round 3
// 2330.155 us; speedup vs baseline: 1.2032x; 1.1001x over previous
//
#include <hip/hip_runtime.h>
#include <cstdint>
#include <cstddef>

#define SS 12
#define NN 16384
#define EE 262144
#define TT 3072          // SS*NN/BB

typedef _Float16 h2_t __attribute__((ext_vector_type(2)));
typedef short bf16x8 __attribute__((ext_vector_type(8)));
typedef float floatx4 __attribute__((ext_vector_type(4)));
typedef unsigned short ushortx8 __attribute__((ext_vector_type(8)));

// ---------- helpers ----------
__device__ __forceinline__ float fast_sig(float x) {
    float e = __builtin_amdgcn_exp2f(-1.442695041f * x);   // exp(-x)
    return __builtin_amdgcn_rcpf(1.f + e);
}
__device__ __forceinline__ float fast_tanh(float x) {
    float e = __builtin_amdgcn_exp2f(2.885390082f * x);    // exp(2x); inf-safe
    return 1.f - 2.f * __builtin_amdgcn_rcpf(e + 1.f);
}
__device__ __forceinline__ unsigned short f2bf(float f) {
    unsigned int x = __float_as_uint(f);
    unsigned int r = (x + 0x7FFFu + ((x >> 16) & 1u)) >> 16;
    return (unsigned short)r;
}
__device__ __forceinline__ float bf2f(unsigned short u) {
    return __uint_as_float(((unsigned int)u) << 16);
}
// quad_perm(1,0,3,2): swap lane l ^ 1
__device__ __forceinline__ float dpp_xor1(float x) {
    int i = __builtin_amdgcn_mov_dpp(__float_as_int(x), 0xB1, 0xF, 0xF, true);
    return __int_as_float(i);
}
// quad_perm(2,3,0,1): swap lane l ^ 2
__device__ __forceinline__ float dpp_xor2(float x) {
    int i = __builtin_amdgcn_mov_dpp(__float_as_int(x), 0x4E, 0xF, 0xF, true);
    return __int_as_float(i);
}

// ---------- zero counts ----------
__global__ void k_zero(int* __restrict__ p) {
    p[blockIdx.x * 256 + threadIdx.x] = 0;
}

// ---------- CSR build ----------
__global__ void k_count(const int* __restrict__ adj, int* __restrict__ counts) {
    int i = blockIdx.x * 256 + threadIdx.x;          // over SS*EE
    int t = i / EE, e = i - t * EE;
    int dst = adj[(size_t)t * 2 * EE + e];
    atomicAdd(&counts[t * NN + dst], 1);
}

__global__ void k_scan(const int* __restrict__ counts, int* __restrict__ offs,
                       int* __restrict__ cursor) {
    __shared__ int sums[1024];
    int t = blockIdx.x, tid = threadIdx.x;
    const int per = NN / 1024;                       // 16
    int base = t * NN + tid * per;
    int local[16];
    int s = 0;
#pragma unroll
    for (int i = 0; i < per; i++) { local[i] = counts[base + i]; s += local[i]; }
    sums[tid] = s;
    __syncthreads();
    for (int off = 1; off < 1024; off <<= 1) {
        int v = (tid >= off) ? sums[tid - off] : 0;
        __syncthreads();
        sums[tid] += v;
        __syncthreads();
    }
    int run = sums[tid] - s;                         // exclusive
#pragma unroll
    for (int i = 0; i < per; i++) { offs[base + i] = run; cursor[base + i] = run; run += local[i]; }
}

__global__ void k_scatter(const int* __restrict__ adj, const float* __restrict__ vals,
                          int* __restrict__ cursor, int2* __restrict__ edges) {
    int i = blockIdx.x * 256 + threadIdx.x;
    int t = i / EE, e = i - t * EE;
    int dst = adj[(size_t)t * 2 * EE + e];
    int src = adj[(size_t)t * 2 * EE + EE + e];
    float v = vals[(size_t)t * EE + e];
    int p = atomicAdd(&cursor[t * NN + dst], 1);
    edges[(size_t)t * EE + p] = make_int2(src, __float_as_int(v));
}

// ---------- support = xs @ gcn_weight  (fp32 acc, bf16 out) ----------
__global__ __launch_bounds__(256) void k_support(const float* __restrict__ xs,
                                                 const float* __restrict__ W,
                                                 unsigned short* __restrict__ sup) {
    __shared__ float Ash[64][128];
    __shared__ float Wsh[128][128];
    int tid = threadIdx.x;
    size_t rowbase = (size_t)blockIdx.x * 64;
    const float4* xa = (const float4*)(xs + rowbase * 128);
    float4* As = (float4*)&Ash[0][0];
#pragma unroll
    for (int q = 0; q < 8; q++) As[tid + q * 256] = xa[tid + q * 256];
    const float4* wg = (const float4*)W;
    float4* Ws = (float4*)&Wsh[0][0];
#pragma unroll
    for (int q = 0; q < 16; q++) Ws[tid + q * 256] = wg[tid + q * 256];
    __syncthreads();
    int jg = tid & 31, rg = tid >> 5;
    float acc[8][4];
#pragma unroll
    for (int i = 0; i < 8; i++)
#pragma unroll
        for (int j = 0; j < 4; j++) acc[i][j] = 0.f;
    for (int k4 = 0; k4 < 128; k4 += 4) {
        float4 a[8];
#pragma unroll
        for (int i = 0; i < 8; i++) a[i] = *(const float4*)&Ash[rg * 8 + i][k4];
#pragma unroll
        for (int kk = 0; kk < 4; kk++) {
            float4 wv = *(const float4*)&Wsh[k4 + kk][jg * 4];
#pragma unroll
            for (int i = 0; i < 8; i++) {
                float av = (kk == 0) ? a[i].x : (kk == 1) ? a[i].y : (kk == 2) ? a[i].z : a[i].w;
                acc[i][0] += av * wv.x; acc[i][1] += av * wv.y;
                acc[i][2] += av * wv.z; acc[i][3] += av * wv.w;
            }
        }
    }
#pragma unroll
    for (int i = 0; i < 8; i++) {
        ushort4 o;
        o.x = f2bf(acc[i][0]); o.y = f2bf(acc[i][1]);
        o.z = f2bf(acc[i][2]); o.w = f2bf(acc[i][3]);
        *(ushort4*)&sup[(rowbase + rg * 8 + i) * 128 + jg * 4] = o;
    }
}

// ---------- gather-reduce: wave per node, 2 dims per lane ----------
__global__ __launch_bounds__(256) void k_gather(const int2* __restrict__ edges,
                         const int* __restrict__ offs,
                         const int* __restrict__ ends,
                         const unsigned short* __restrict__ sup,
                         const float* __restrict__ bias,
                         unsigned short* __restrict__ cur) {
    int bn = blockIdx.x * 4 + (threadIdx.x >> 6);     // t*NN + n, wave-uniform
    bn = __builtin_amdgcn_readfirstlane(bn);
    int t = bn >> 14;
    int l = threadIdx.x & 63;
    int beg = offs[bn];
    int end = ends[bn];
    const unsigned short* supt = sup + (size_t)t * NN * 128;
    const int2* eg = edges + (size_t)t * EE;
    float acc0 = 0.f, acc1 = 0.f;                     // dims 2l, 2l+1
    int p = beg;
    for (; p + 3 < end; p += 4) {
        int2 e0 = eg[p], e1 = eg[p + 1], e2 = eg[p + 2], e3 = eg[p + 3];
        unsigned int u0 = *(const unsigned int*)&supt[(size_t)e0.x * 128 + 2 * l];
        unsigned int u1 = *(const unsigned int*)&supt[(size_t)e1.x * 128 + 2 * l];
        unsigned int u2 = *(const unsigned int*)&supt[(size_t)e2.x * 128 + 2 * l];
        unsigned int u3 = *(const unsigned int*)&supt[(size_t)e3.x * 128 + 2 * l];
        float w0 = __int_as_float(e0.y), w1 = __int_as_float(e1.y);
        float w2 = __int_as_float(e2.y), w3 = __int_as_float(e3.y);
        acc0 += w0 * bf2f((unsigned short)u0); acc1 += w0 * bf2f((unsigned short)(u0 >> 16));
        acc0 += w1 * bf2f((unsigned short)u1); acc1 += w1 * bf2f((unsigned short)(u1 >> 16));
        acc0 += w2 * bf2f((unsigned short)u2); acc1 += w2 * bf2f((unsigned short)(u2 >> 16));
        acc0 += w3 * bf2f((unsigned short)u3); acc1 += w3 * bf2f((unsigned short)(u3 >> 16));
    }
    for (; p < end; p++) {
        int2 e0 = eg[p];
        unsigned int u0 = *(const unsigned int*)&supt[(size_t)e0.x * 128 + 2 * l];
        float w0 = __int_as_float(e0.y);
        acc0 += w0 * bf2f((unsigned short)u0);
        acc1 += w0 * bf2f((unsigned short)(u0 >> 16));
    }
    float r0 = acc0 + bias[2 * l];
    float r1 = acc1 + bias[2 * l + 1];
    ushort2 o;
    o.x = f2bf(r0 > 0.f ? r0 : 0.f);
    o.y = f2bf(r1 > 0.f ? r1 : 0.f);
    *(ushort2*)&cur[(size_t)bn * 128 + 2 * l] = o;
}

// ---------- gates_x = cur @ w_ih^T + (b_ih+b_hh), bf16 MFMA ----------
// grid (3072, 8), 256 thr. Block: rows 64 (M), gates 64 (N), K=128.
// Output layout for k_lstm: element j's 4 gates (i,f,g,o) contiguous:
//   slot = j*4 + gate_idx   (gate_idx = gcol>>7, j = gcol&127)
// so k_lstm thread owning element j does ONE aligned 8B load per step.
__global__ __launch_bounds__(256) void k_xgates(const unsigned short* __restrict__ cur,
                                                const float* __restrict__ wih,
                                                const float* __restrict__ bih,
                                                const float* __restrict__ bhh,
                                                unsigned short* __restrict__ gx) {
    __shared__ __align__(16) unsigned short At[64][136];   // +8 pad: 2-way banks
    __shared__ __align__(16) unsigned short Bt[64][136];
    int tid = threadIdx.x;
    size_t rowbase = (size_t)blockIdx.x * 64;
    int gbase = blockIdx.y * 64;
    // A tile: 64x128 bf16, 16B chunks
#pragma unroll
    for (int q = 0; q < 4; q++) {
        int idx = tid + q * 256;          // 0..1023 (16 chunks per row)
        int r = idx >> 4;
        int cc = (idx & 15) * 8;
        *(ushortx8*)&At[r][cc] = *(const ushortx8*)&cur[(rowbase + r) * 128 + cc];
    }
    // B tile: wih rows gbase..gbase+64, fp32 -> bf16 on the fly
#pragma unroll
    for (int q = 0; q < 8; q++) {
        int idx = tid + q * 256;          // 0..2047 (32 float4 per row)
        int r = idx >> 5;
        int c4 = (idx & 31) * 4;
        float4 v = *(const float4*)&wih[(size_t)(gbase + r) * 128 + c4];
        ushort4 o;
        o.x = f2bf(v.x); o.y = f2bf(v.y); o.z = f2bf(v.z); o.w = f2bf(v.w);
        *(ushort4*)&Bt[r][c4] = o;
    }
    __syncthreads();
    int wave = tid >> 6, lane = tid & 63;
    int m0 = wave * 16;
    int rin = lane & 15;
    int koff = (lane >> 4) * 8;
    floatx4 acc[4];
#pragma unroll
    for (int n = 0; n < 4; n++) acc[n] = (floatx4){0.f, 0.f, 0.f, 0.f};
#pragma unroll
    for (int kc = 0; kc < 4; kc++) {
        bf16x8 a = *(const bf16x8*)&At[m0 + rin][kc * 32 + koff];
#pragma unroll
        for (int n = 0; n < 4; n++) {
            bf16x8 b = *(const bf16x8*)&Bt[n * 16 + rin][kc * 32 + koff];
            acc[n] = __builtin_amdgcn_mfma_f32_16x16x32_bf16(a, b, acc[n], 0, 0, 0);
        }
    }
    // C/D: col = lane&15, row = (lane>>4)*4 + reg
    int rq = (lane >> 4) * 4;
#pragma unroll
    for (int n = 0; n < 4; n++) {
        int gcol = gbase + n * 16 + rin;
        float bs = bih[gcol] + bhh[gcol];
        int slot = ((gcol & 127) << 2) | (gcol >> 7);
#pragma unroll
        for (int i = 0; i < 4; i++) {
            size_t row = rowbase + m0 + rq + i;
            gx[row * 512 + slot] = f2bf(acc[n][i] + bs);
        }
    }
}

// ---------- persistent LSTM: 64 blocks x 256 thr, quad-K-split ----------
// Quad Q = tid>>2 owns hidden elements {2Q, 2Q+1}. Lane ll = tid&3 owns
// K-chunk [32*ll, 32*ll+32) of h, held in VGPRs (re-read from LDS each step
// via 4x ds_read_b128). Each lane holds weight slices for all 8 (gate,elem)
// rows of its quad over its K-chunk: 8x16 h2 = 128 VGPRs (1 block/CU ->
// full 512-VGPR budget available). Dot = 128 fdot2 in 8 independent VGPR
// chains: NO readlane, NO SGPR hazards. Quad reduce = 2 DPP butterfly
// stages. Thread keeps element j = 2Q + ((tid>>1)&1); computes i,f,g,o
// activations with fixed roles (no divergence). gx pre-packed by k_xgates
// as (i,f,g,o) per element: one 8B load/step, register ring 3 deep.
// h double-buffered in LDS: exactly ONE barrier per step. out stored in
// bursts of 8 steps to keep the vmcnt queue shallow.
__global__ __launch_bounds__(256, 1) void k_lstm(const unsigned short* __restrict__ gx,
                                                 const float* __restrict__ whh,
                                                 const float* __restrict__ h0,
                                                 const float* __restrict__ c0,
                                                 float* __restrict__ out) {
    __shared__ __align__(16) _Float16 hsh[2][128];   // double-buffered h (f16)
    int b = blockIdx.x, tid = threadIdx.x;
    int Q = tid >> 2;                 // 0..63
    int ll = tid & 3;                 // K-chunk
    int p = (tid >> 1) & 1;           // which element of the quad
    int j = 2 * Q + p;                // hidden element owned (pair-redundant)

    // weights: rows (g*128 + 2Q + e) for g8 = e*4 + g, cols [32*ll, 32*ll+32)
    h2_t wreg[8][16];
#pragma unroll
    for (int g8 = 0; g8 < 8; g8++) {
        int row = (g8 & 3) * 128 + 2 * Q + (g8 >> 2);
        const float4* rp = (const float4*)(whh + (size_t)row * 128 + ll * 32);
#pragma unroll
        for (int q4 = 0; q4 < 8; q4++) {
            float4 v = rp[q4];
            h2_t a; a.x = (_Float16)v.x; a.y = (_Float16)v.y;
            h2_t bq; bq.x = (_Float16)v.z; bq.y = (_Float16)v.w;
            wreg[g8][2 * q4] = a; wreg[g8][2 * q4 + 1] = bq;
        }
    }
    float c = c0[(size_t)b * 128 + j];               // pair-redundant copy
    if (tid < 128) hsh[0][tid] = (_Float16)h0[(size_t)b * 128 + tid];
    __syncthreads();

    // gx ring: one 8B value per thread per step, 3 deep
    const unsigned short* gxb = gx + (size_t)b * 512 + 4 * j;   // +t*32768
    uint2 rg0 = *(const uint2*)(gxb);
    uint2 rg1 = *(const uint2*)(gxb + 32768);
    uint2 rg2 = *(const uint2*)(gxb + 2 * (size_t)32768);

#define LSTM_STEP(T, RD, WR, QIDX)                                          \
    {                                                                       \
        const h2_t* hp_ = (const h2_t*)&hsh[RD][32 * ll];                   \
        h2_t hs_[16];                                                       \
        _Pragma("unroll")                                                   \
        for (int kk = 0; kk < 16; kk++) hs_[kk] = hp_[kk];                  \
        float part_[8];                                                     \
        _Pragma("unroll")                                                   \
        for (int g8 = 0; g8 < 8; g8++) part_[g8] = 0.f;                     \
        _Pragma("unroll")                                                   \
        for (int kk = 0; kk < 16; kk++) {                                   \
            _Pragma("unroll")                                               \
            for (int g8 = 0; g8 < 8; g8++)                                  \
                part_[g8] = __builtin_amdgcn_fdot2(wreg[g8][kk], hs_[kk],   \
                                                   part_[g8], false);       \
        }                                                                   \
        _Pragma("unroll")                                                   \
        for (int g8 = 0; g8 < 8; g8++) part_[g8] += dpp_xor1(part_[g8]);    \
        _Pragma("unroll")                                                   \
        for (int g8 = 0; g8 < 8; g8++) part_[g8] += dpp_xor2(part_[g8]);    \
        float si_ = p ? part_[4] : part_[0];                                \
        float sf_ = p ? part_[5] : part_[1];                                \
        float sg_ = p ? part_[6] : part_[2];                                \
        float so_ = p ? part_[7] : part_[3];                                \
        uint2 gv_ = rg0;                                                    \
        float ri_ = si_ + bf2f((unsigned short)(gv_.x & 0xffffu));          \
        float rf_ = sf_ + bf2f((unsigned short)(gv_.x >> 16));              \
        float rgg_ = sg_ + bf2f((unsigned short)(gv_.y & 0xffffu));         \
        float ro_ = so_ + bf2f((unsigned short)(gv_.y >> 16));              \
        float ai_ = fast_sig(ri_);                                          \
        float af_ = fast_sig(rf_);                                          \
        float ag_ = fast_tanh(rgg_);                                        \
        float ao_ = fast_sig(ro_);                                          \
        c = af_ * c + ai_ * ag_;                                            \
        float hn_ = ao_ * fast_tanh(c);                                     \
        hh8[QIDX] = hn_;                                                    \
        if ((tid & 1) == 0) hsh[WR][j] = (_Float16)hn_;                     \
        rg0 = rg1; rg1 = rg2;                                               \
        {                                                                   \
            int tp_ = ((T) + 3 < TT) ? (T) + 3 : TT - 1;                    \
            rg2 = *(const uint2*)(gxb + (size_t)tp_ * 32768);               \
        }                                                                   \
        __syncthreads();                                                    \
    }

    for (int t8 = 0; t8 < TT; t8 += 8) {
        float hh8[8];
        LSTM_STEP(t8 + 0, 0, 1, 0);
        LSTM_STEP(t8 + 1, 1, 0, 1);
        LSTM_STEP(t8 + 2, 0, 1, 2);
        LSTM_STEP(t8 + 3, 1, 0, 3);
        LSTM_STEP(t8 + 4, 0, 1, 4);
        LSTM_STEP(t8 + 5, 1, 0, 5);
        LSTM_STEP(t8 + 6, 0, 1, 6);
        LSTM_STEP(t8 + 7, 1, 0, 7);
        if ((tid & 1) == 0) {
#pragma unroll
            for (int q = 0; q < 8; q++)
                out[((size_t)(t8 + q) * 64 + b) * 128 + j] = hh8[q];
        }
    }
#undef LSTM_STEP
}

// ---------- launcher ----------
extern "C" void kernel_launch(void* const* d_in, const int* in_sizes, int n_in,
                              void* d_out, int out_size, void* d_ws, size_t ws_size,
                              hipStream_t stream) {
    const int* adj    = (const int*)d_in[0];
    const float* vals = (const float*)d_in[1];
    const float* xs   = (const float*)d_in[2];
    const float* gw   = (const float*)d_in[3];
    const float* gb   = (const float*)d_in[4];
    const float* wih  = (const float*)d_in[5];
    const float* whh  = (const float*)d_in[6];
    const float* bih  = (const float*)d_in[7];
    const float* bhh  = (const float*)d_in[8];
    const float* h0   = (const float*)d_in[9];
    const float* c0   = (const float*)d_in[10];
    float* out = (float*)d_out;

    // Workspace layout (peak concurrent = 251,658,240 B):
    //   [0, 50,331,648)             cur (bf16, S*N*128)
    //   [50,331,648, 251,658,240)   gx  (bf16, S*N*512)
    // Aliased INSIDE the gx region (dead before k_xgates writes gx):
    //   support @ gx+0, counts/offs/cursor/edges after it.
    char* ws = (char*)d_ws;
    unsigned short* cur = (unsigned short*)(ws);
    unsigned short* gx  = (unsigned short*)(ws + 50331648);
    unsigned short* sup = (unsigned short*)(ws + 50331648);
    int* counts         = (int*)(ws + 100663296);
    int* offs           = (int*)(ws + 101449728);
    int* cursor         = (int*)(ws + 102236160);
    int2* edges         = (int2*)(ws + 103022592);

    k_zero<<<(SS * NN) / 256, 256, 0, stream>>>(counts);
    k_count<<<(SS * EE) / 256, 256, 0, stream>>>(adj, counts);
    k_scan<<<SS, 1024, 0, stream>>>(counts, offs, cursor);
    k_scatter<<<(SS * EE) / 256, 256, 0, stream>>>(adj, vals, cursor, edges);
    k_support<<<(SS * NN) / 64, 256, 0, stream>>>(xs, gw, sup);
    k_gather<<<(SS * NN) / 4, 256, 0, stream>>>(edges, offs, cursor, sup, gb, cur);
    k_xgates<<<dim3((SS * NN) / 64, 8), 256, 0, stream>>>(cur, wih, bih, bhh, gx);
    k_lstm<<<64, 256, 0, stream>>>(gx, whh, h0, c0, out);
}